// Round 2
// baseline (1939.430 us; speedup 1.0000x reference)
//
#include <hip/hip_runtime.h>
#include <hip/hip_bf16.h>
#include <stdint.h>

typedef __attribute__((ext_vector_type(8))) short bf16x8;
typedef __attribute__((ext_vector_type(4))) float f32x4;
typedef __hip_bfloat16 bf16;

typedef const __attribute__((address_space(1))) void* gas_ptr;
typedef __attribute__((address_space(3))) void* las_ptr;

__device__ __forceinline__ void async_load16(const bf16* g, bf16* l) {
  __builtin_amdgcn_global_load_lds((gas_ptr)g, (las_ptr)l, 16, 0, 0);
}

// fp32 -> bf16 conversion, 8 elements/thread (32B in, 16B out per lane).
__global__ __launch_bounds__(256) void cvt_kernel(
    const float* __restrict__ in, bf16* __restrict__ out, int n8) {
  int i = blockIdx.x * blockDim.x + threadIdx.x;
  if (i >= n8) return;
  const float4* p = (const float4*)in;
  float4 a = p[2 * i], b = p[2 * i + 1];
  union { bf16x8 v; bf16 h[8]; } u;
  u.h[0] = __float2bfloat16(a.x); u.h[1] = __float2bfloat16(a.y);
  u.h[2] = __float2bfloat16(a.z); u.h[3] = __float2bfloat16(a.w);
  u.h[4] = __float2bfloat16(b.x); u.h[5] = __float2bfloat16(b.y);
  u.h[6] = __float2bfloat16(b.z); u.h[7] = __float2bfloat16(b.w);
  ((bf16x8*)out)[i] = u.v;
}

// C[m,n] = sum_k A[m,k] * B[n,k] (+ bias[n]); A,B bf16, fp32 accum, OutT out.
// 128x128 tile, BK=32, 256 threads = 4 waves in 2x2, each wave 4x4 of 16x16x32 MFMA.
template <int BIAS, typename OutT>
__global__ __launch_bounds__(256, 2) void gemm_bt_kernel(
    const bf16* __restrict__ A, const bf16* __restrict__ B,
    const float* __restrict__ bias, OutT* __restrict__ C,
    int M, int N, int K) {
  __shared__ __attribute__((aligned(16))) bf16 As[128 * 32];
  __shared__ __attribute__((aligned(16))) bf16 Bs[128 * 32];

  const int tid  = threadIdx.x;
  const int lane = tid & 63;
  const int wv   = tid >> 6;
  const int wm   = wv & 1;
  const int wn   = wv >> 1;
  const int quad = lane >> 4;
  const int l15  = lane & 15;
  const int m0 = blockIdx.y * 128;
  const int n0 = blockIdx.x * 128;

  f32x4 acc[4][4];
  const f32x4 zero = {0.f, 0.f, 0.f, 0.f};
#pragma unroll
  for (int i = 0; i < 4; ++i)
#pragma unroll
    for (int j = 0; j < 4; ++j) acc[i][j] = zero;

  for (int k0 = 0; k0 < K; k0 += 32) {
    // Stage A,B tiles (128x32 bf16) via global_load_lds width=16.
    // chunk c = wv*128 + call*64 + lane; row r = c>>2, k-chunk jj = c&3.
    // HW writes lane L at wave-uniform base + L*16B -> chunk index matches c.
#pragma unroll
    for (int call = 0; call < 2; ++call) {
      const int c = wv * 128 + call * 64 + lane;
      const int r = c >> 2;
      const int jj = c & 3;
      const size_t ga = (size_t)(m0 + r) * K + k0 + jj * 8;
      const size_t gb = (size_t)(n0 + r) * K + k0 + jj * 8;
      async_load16(A + ga, As + (wv * 128 + call * 64) * 8);
      async_load16(B + gb, Bs + (wv * 128 + call * 64) * 8);
    }
    __syncthreads();  // compiler drains vmcnt before s_barrier

    bf16x8 af[4], bfr[4];
#pragma unroll
    for (int t = 0; t < 4; ++t) {
      af[t]  = *(const bf16x8*)(As + (wm * 64 + t * 16 + l15) * 32 + quad * 8);
      bfr[t] = *(const bf16x8*)(Bs + (wn * 64 + t * 16 + l15) * 32 + quad * 8);
    }
#pragma unroll
    for (int tm = 0; tm < 4; ++tm)
#pragma unroll
      for (int tn = 0; tn < 4; ++tn)
        acc[tm][tn] = __builtin_amdgcn_mfma_f32_16x16x32_bf16(
            af[tm], bfr[tn], acc[tm][tn], 0, 0, 0);
    __syncthreads();  // protect LDS before next stage overwrites
  }

  // Epilogue. C/D layout (m89-verified): col = lane&15, row = quad*4 + reg.
#pragma unroll
  for (int tm = 0; tm < 4; ++tm) {
    const int row0 = m0 + wm * 64 + tm * 16 + quad * 4;
#pragma unroll
    for (int tn = 0; tn < 4; ++tn) {
      const int col = n0 + wn * 64 + tn * 16 + l15;
      float bv = 0.f;
      if (BIAS) bv = bias[col];
#pragma unroll
      for (int i = 0; i < 4; ++i) {
        float v = acc[tm][tn][i] + bv;
        if constexpr (sizeof(OutT) == 2)
          C[(size_t)(row0 + i) * N + col] = __float2bfloat16(v);
        else
          C[(size_t)(row0 + i) * N + col] = v;
      }
    }
  }
}

// Per-token head-attention: one block per token.
// qkv[b, s, h, d] (s=0:q,1:k,2:v), S = softmax(QK^T * hd^-0.5) over g,
// O[h,d] = sum_g P[h,g] V[g,d]; output layout out[b, d*32 + h].
__global__ __launch_bounds__(256) void attn_kernel(
    const bf16* __restrict__ qkv, bf16* __restrict__ out) {
  const int b = blockIdx.x;
  const int tid = threadIdx.x;
  // rows padded: 128 bf16 -> 130 bf16 (65 uints) so K/V row reads are conflict-free
  __shared__ uint32_t sQKV[3 * 32 * 65];
  __shared__ float S[32][33];

  const uint32_t* src = (const uint32_t*)(qkv + (size_t)b * 12288);
#pragma unroll
  for (int i = 0; i < 24; ++i) {
    int c = tid + i * 256;       // 0..6143 uint chunks (2 bf16 each)
    int sec = c >> 11;           // 0:q 1:k 2:v
    int cc = c & 2047;
    int row = cc >> 6;
    int col = cc & 63;
    sQKV[sec * 2080 + row * 65 + col] = src[c];
  }
  __syncthreads();

  const float scale = 0.088388347648318447f;  // 1/sqrt(128)
#pragma unroll
  for (int i = 0; i < 4; ++i) {
    int p = tid + i * 256;       // 0..1023 -> (h,g)
    int h = p >> 5;
    int g = p & 31;
    const __hip_bfloat162* qr = (const __hip_bfloat162*)(sQKV + h * 65);
    const __hip_bfloat162* kr = (const __hip_bfloat162*)(sQKV + 2080 + g * 65);
    float acc = 0.f;
#pragma unroll
    for (int d = 0; d < 64; ++d) {
      float2 qf = __bfloat1622float2(qr[d]);
      float2 kf = __bfloat1622float2(kr[d]);
      acc = fmaf(qf.x, kf.x, acc);
      acc = fmaf(qf.y, kf.y, acc);
    }
    S[h][g] = acc * scale;
  }
  __syncthreads();

  if (tid < 32) {
    float m = -1e30f;
#pragma unroll
    for (int g = 0; g < 32; ++g) m = fmaxf(m, S[tid][g]);
    float sum = 0.f;
#pragma unroll
    for (int g = 0; g < 32; ++g) {
      float e = __expf(S[tid][g] - m);
      S[tid][g] = e;
      sum += e;
    }
    float inv = 1.f / sum;
#pragma unroll
    for (int g = 0; g < 32; ++g) S[tid][g] *= inv;
  }
  __syncthreads();

  const bf16* V = (const bf16*)(sQKV + 2 * 2080);
  bf16* orow = out + (size_t)b * 4096;
#pragma unroll
  for (int i = 0; i < 16; ++i) {
    int c = tid + i * 256;  // linear out index = d*32 + h (coalesced store)
    int d = c >> 5;
    int h = c & 31;
    float acc = 0.f;
#pragma unroll
    for (int g = 0; g < 32; ++g)
      acc = fmaf(S[h][g], __bfloat162float(V[g * 130 + d]), acc);
    orow[c] = __float2bfloat16(acc);
  }
}

extern "C" void kernel_launch(void* const* d_in, const int* in_sizes, int n_in,
                              void* d_out, int out_size, void* d_ws, size_t ws_size,
                              hipStream_t stream) {
  // Reference dtypes are float32 (inputs AND output). bf16 is internal only.
  const float* x      = (const float*)d_in[0];
  const float* w_qkv  = (const float*)d_in[1];
  const float* w_proj = (const float*)d_in[2];
  const float* b_proj = (const float*)d_in[3];
  float* out = (float*)d_out;

  const int C = in_sizes[3];           // 4096
  const int B = in_sizes[0] / C;       // 8192

  // Workspace layout (bytes): xb [0, 64MiB) | wqb [64MiB, 160MiB) | qkvb [160MiB, 352MiB)
  // xb is reused for attn_out after GEMM1; wqb is reused for w_proj_bf16 after GEMM1.
  bf16* xb    = (bf16*)d_ws;                    // B*C bf16
  bf16* wqb   = xb + (size_t)B * C;             // 3C*C bf16
  bf16* qkvb  = wqb + (size_t)3 * C * C;        // B*3C bf16
  bf16* attnb = xb;                             // reuse (x dead after GEMM1)
  bf16* wpb   = wqb;                            // reuse (w_qkv dead after GEMM1)

  const int nx = B * C / 8, nwq = 3 * C * C / 8, nwp = C * C / 8;
  cvt_kernel<<<(nx + 255) / 256, 256, 0, stream>>>(x, xb, nx);
  cvt_kernel<<<(nwq + 255) / 256, 256, 0, stream>>>(w_qkv, wqb, nwq);

  // 1) qkv = x @ w_qkv.T  (bf16 out)
  gemm_bt_kernel<0, bf16><<<dim3(3 * C / 128, B / 128), 256, 0, stream>>>(
      xb, wqb, nullptr, qkvb, B, 3 * C, C);
  // 2) per-token head attention (+ transpose to (d*H + h) layout)
  attn_kernel<<<B, 256, 0, stream>>>(qkvb, attnb);
  // 3) out = attn_out @ w_proj.T + b_proj  (fp32 out)
  cvt_kernel<<<(nwp + 255) / 256, 256, 0, stream>>>(w_proj, wpb, nwp);
  gemm_bt_kernel<1, float><<<dim3(C / 128, B / 128), 256, 0, stream>>>(
      attnb, wpb, b_proj, out, B, C, C);
}